// Round 8
// baseline (657.310 us; speedup 1.0000x reference)
//
#include <hip/hip_runtime.h>

#define BB 4
#define CC 256
#define NN 4096
#define CNT (CC*NN)

typedef float f32x4 __attribute__((ext_vector_type(4)));
typedef float f32x16 __attribute__((ext_vector_type(16)));
typedef short bf16x8 __attribute__((ext_vector_type(8)));

__device__ inline ushort f2bf(float f) {
    union { float f; uint u; } v; v.f = f;
    uint r = v.u + 0x7fff + ((v.u >> 16) & 1);
    return (ushort)(r >> 16);
}

#define MFMA16(d, a, b) d = __builtin_amdgcn_mfma_f32_16x16x32_bf16(a, b, d, 0, 0, 0)
#define MFMA32(d, a, b) d = __builtin_amdgcn_mfma_f32_32x32x16_bf16(a, b, d, 0, 0, 0)

// ---------------- stats: deterministic two-stage sum/sumsq per batch ----------------
__global__ __launch_bounds__(256) void stats_part(const float* __restrict__ x,
                                                  float* __restrict__ part) {
    int b = blockIdx.y;
    const float* xb = x + b * CNT;
    float s = 0.f, q = 0.f;
    int base = (blockIdx.x * 256 + threadIdx.x) * 4;
    for (int i = base; i < CNT; i += 64 * 256 * 4) {
        f32x4 v = *(const f32x4*)(xb + i);
        s += (v.x + v.y) + (v.z + v.w);
        q += (v.x * v.x + v.y * v.y) + (v.z * v.z + v.w * v.w);
    }
    for (int off = 32; off; off >>= 1) {
        s += __shfl_down(s, off, 64);
        q += __shfl_down(q, off, 64);
    }
    __shared__ float red[8];
    int lane = threadIdx.x & 63, wv = threadIdx.x >> 6;
    if (!lane) { red[wv * 2] = s; red[wv * 2 + 1] = q; }
    __syncthreads();
    if (threadIdx.x == 0) {
        part[(b * 64 + blockIdx.x) * 2 + 0] = red[0] + red[2] + red[4] + red[6];
        part[(b * 64 + blockIdx.x) * 2 + 1] = red[1] + red[3] + red[5] + red[7];
    }
}

__global__ __launch_bounds__(256) void stats_final(const float* __restrict__ part,
                                                   float* __restrict__ stats) {
    int t = threadIdx.x;
    int b = t >> 6, lane = t & 63;
    float s = part[(b * 64 + lane) * 2 + 0];
    float q = part[(b * 64 + lane) * 2 + 1];
    for (int off = 32; off; off >>= 1) {
        s += __shfl_down(s, off, 64);
        q += __shfl_down(q, off, 64);
    }
    if (lane == 0) { stats[b * 2] = s; stats[b * 2 + 1] = q; }
}

// ---------------- norm + transpose: x[b][c][n] fp32 -> xn_t[b][n][c] bf16 ----------------
__global__ __launch_bounds__(256) void norm_t_kernel(
    const float* __restrict__ x, const float* __restrict__ gamma,
    const float* __restrict__ beta, const float* __restrict__ stats,
    ushort* __restrict__ xn_t)
{
    int b = blockIdx.z;
    float mean = stats[b * 2] * (1.0f / (float)CNT);
    float var = stats[b * 2 + 1] * (1.0f / (float)CNT) - mean * mean;
    float rinv = rsqrtf(var + 1e-5f);
    int n0 = blockIdx.x * 32, c0 = blockIdx.y * 32;
    __shared__ float tl[32][33];
    int tr = threadIdx.x >> 3;
    int tc4 = (threadIdx.x & 7) * 4;
    int c = c0 + tr;
    float gsc = gamma[c] * rinv;
    float bsc = beta[c] - mean * gsc;
    f32x4 v = *(const f32x4*)(x + ((b * CC + c) * NN + n0 + tc4));
    tl[tr][tc4 + 0] = v.x * gsc + bsc;
    tl[tr][tc4 + 1] = v.y * gsc + bsc;
    tl[tr][tc4 + 2] = v.z * gsc + bsc;
    tl[tr][tc4 + 3] = v.w * gsc + bsc;
    __syncthreads();
    int nr = threadIdx.x >> 3;
    int cg4 = (threadIdx.x & 7) * 4;
    ushort4 o;
    o.x = f2bf(tl[cg4 + 0][nr]);
    o.y = f2bf(tl[cg4 + 1][nr]);
    o.z = f2bf(tl[cg4 + 2][nr]);
    o.w = f2bf(tl[cg4 + 3][nr]);
    *(ushort4*)(xn_t + ((size_t)(b * NN + n0 + nr) * CC + c0 + cg4)) = o;
}

// ---------------- QKV GEMM: [768,256]x[256,4096] per batch, bf16 MFMA ----------------
// Q rows are PRE-SCALED by 2^-4 (= C^-0.5) so flash needs no scale.
__global__ __launch_bounds__(256) void qkv_kernel(
    const ushort* __restrict__ xn_t, const float* __restrict__ qkv_w,
    const float* __restrict__ qkv_b, ushort* __restrict__ q_t,
    ushort* __restrict__ k_t, ushort* __restrict__ v_g)
{
    int b = blockIdx.z;
    int d0 = blockIdx.x * 64;
    int i0 = blockIdx.y * 64;
    int t = threadIdx.x, w = t >> 6, l = t & 63, l15 = l & 15, g = l >> 4;
    __shared__ ushort b_lds[64 * 256];

    #pragma unroll
    for (int it = 0; it < 8; it++) {
        int cid = it * 256 + t;
        int rr = cid >> 5, cc = cid & 31;
        bf16x8 vv = *(const bf16x8*)(xn_t + ((size_t)(b * NN + i0 + rr) * CC + cc * 8));
        *(bf16x8*)(b_lds + rr * 256 + (cc ^ (rr & 7)) * 8) = vv;
    }
    bf16x8 af[8];
    int drow = d0 + w * 16 + l15;
    #pragma unroll
    for (int kk = 0; kk < 8; kk++) {
        const float* ap = qkv_w + drow * CC + kk * 32 + g * 8;
        f32x4 u0 = *(const f32x4*)ap;
        f32x4 u1 = *(const f32x4*)(ap + 4);
        bf16x8 a;
        a[0] = (short)f2bf(u0.x); a[1] = (short)f2bf(u0.y);
        a[2] = (short)f2bf(u0.z); a[3] = (short)f2bf(u0.w);
        a[4] = (short)f2bf(u1.x); a[5] = (short)f2bf(u1.y);
        a[6] = (short)f2bf(u1.z); a[7] = (short)f2bf(u1.w);
        af[kk] = a;
    }
    __syncthreads();

    f32x4 acc[4];
    #pragma unroll
    for (int it = 0; it < 4; it++) { f32x4 z = {0.f, 0.f, 0.f, 0.f}; acc[it] = z; }
    #pragma unroll
    for (int kk = 0; kk < 8; kk++) {
        int cc = kk * 4 + g;
        #pragma unroll
        for (int it = 0; it < 4; it++) {
            int il = it * 16 + l15;
            bf16x8 bf = *(const bf16x8*)(b_lds + il * 256 + (cc ^ (il & 7)) * 8);
            MFMA16(acc[it], af[kk], bf);
        }
    }
    int dbase = d0 + w * 16 + g * 4;
    f32x4 bias = *(const f32x4*)(qkv_b + dbase);
    float qs = (d0 < 256) ? 0.0625f : 1.0f;
    #pragma unroll
    for (int it = 0; it < 4; it++) {
        int i = i0 + it * 16 + l15;
        if (d0 < 512) {
            ushort4 o;
            o.x = f2bf((acc[it][0] + bias[0]) * qs);
            o.y = f2bf((acc[it][1] + bias[1]) * qs);
            o.z = f2bf((acc[it][2] + bias[2]) * qs);
            o.w = f2bf((acc[it][3] + bias[3]) * qs);
            ushort* dst = (d0 < 256) ? q_t : k_t;
            int dl = dbase - ((d0 < 256) ? 0 : 256);
            *(ushort4*)(dst + ((size_t)(b * NN + i) * CC + dl)) = o;
        } else {
            #pragma unroll
            for (int e = 0; e < 4; e++)
                v_g[(size_t)(b * CC + (dbase - 512 + e)) * NN + i] = f2bf(acc[it][e] + bias[e]);
        }
    }
}

// ---------------- flash attention: 32x32x16 MFMA, 32 Q-rows/wave, 8 waves ----------------
// No-max softmax; cache-path loads. Staging loads issued ONLY in the short window
// right before the LDS write (after compute) to keep kr/vr liveness minimal: peak
// regs = max(O128+qf64+sj16+..., O128+qf64+kr16+vr16+...) <= 256 -> no spill.
__global__ __launch_bounds__(512, 2) void flash_kernel(
    const ushort* __restrict__ q_t, const ushort* __restrict__ k_t,
    const ushort* __restrict__ v_g, float* __restrict__ O_part,
    float* __restrict__ l_part, int segn)
{
    int b = blockIdx.z, seg = blockIdx.y;
    int i0 = blockIdx.x * 256;
    int jbase = seg * segn;
    int t = threadIdx.x, w = t >> 6, l = t & 63, l31 = l & 31, hi = l >> 5;

    __shared__ ushort k_lds[2][64 * 256];  // [j][chunk16B ^ (j&7)]
    __shared__ ushort v_lds[2][256 * 64];  // [c][chunk16B ^ (c&7)]
    __shared__ ushort p_lds[256 * 32];     // [row][chunk8 ^ (row&3)]

    // Q A-fragments: row = i0 + w*32 + l31, k = kk*16 + hi*8 + e
    bf16x8 qf[16];
    const ushort* qrow = q_t + (size_t)(b * NN + i0 + w * 32 + l31) * CC + hi * 8;
    #pragma unroll
    for (int kk = 0; kk < 16; kk++) qf[kk] = *(const bf16x8*)(qrow + kk * 16);

    f32x16 O[8];
    #pragma unroll
    for (int cb = 0; cb < 8; cb++) {
        #pragma unroll
        for (int e = 0; e < 16; e++) O[cb][e] = 0.f;
    }
    float l_r[16];
    #pragma unroll
    for (int e = 0; e < 16; e++) l_r[e] = 0.f;

    const ushort* kb = k_t + (size_t)b * NN * CC;
    const ushort* vb = v_g + (size_t)b * CC * NN;

    // load + swizzled-write tile at absolute j = jt into buffer d.
    // Called in one place so kr/vr live only across this short window.
    auto stage_tile = [&](int d, int jt) {
        bf16x8 kr[4], vr[4];
        #pragma unroll
        for (int is = 0; is < 4; is++) {
            int s = is * 512 + t;
            int jr = s >> 5, cc = s & 31;
            kr[is] = *(const bf16x8*)(kb + (size_t)(jt + jr) * CC + cc * 8);
            int cr = s >> 3, cv = s & 7;
            vr[is] = *(const bf16x8*)(vb + (size_t)cr * NN + jt + cv * 8);
        }
        #pragma unroll
        for (int is = 0; is < 4; is++) {
            int s = is * 512 + t;
            int jr = s >> 5, cc = s & 31;
            *(bf16x8*)((ushort*)k_lds[d] + jr * 256 + ((cc ^ (jr & 7)) * 8)) = kr[is];
            int cr = s >> 3, cv = s & 7;
            *(bf16x8*)((ushort*)v_lds[d] + cr * 64 + ((cv ^ (cr & 7)) * 8)) = vr[is];
        }
    };

    stage_tile(0, jbase);
    int niter = segn >> 6;

    for (int it = 0; it < niter; it++) {
        int d = it & 1;
        __syncthreads();                     // buf d fully written; prev readers done
        const ushort* kl = k_lds[d];
        const ushort* vl = v_lds[d];

        #pragma unroll
        for (int jh = 0; jh < 2; jh++) {
            // S = Q K^T for col-block jh (32 j)
            f32x16 sj;
            #pragma unroll
            for (int e = 0; e < 16; e++) sj[e] = 0.f;
            int j = jh * 32 + l31;
            int kb0 = j * 256 + hi * 8;
            int xj = (j & 7) * 8;
            __builtin_amdgcn_s_setprio(1);
            #pragma unroll
            for (int kk = 0; kk < 16; kk++) {
                bf16x8 bk = *(const bf16x8*)(kl + ((kb0 + kk * 16) ^ xj));
                MFMA32(sj, qf[kk], bk);
            }
            __builtin_amdgcn_s_setprio(0);

            // p = exp(S); accumulate lane-local l; write P strip (own rows only)
            #pragma unroll
            for (int e = 0; e < 16; e++) {
                float p = __expf(sj[e]);
                l_r[e] += p;
                int row = w * 32 + (e & 3) + 8 * (e >> 2) + 4 * hi;
                p_lds[row * 32 + (((l31 >> 3) ^ (row & 3)) * 8) + (l31 & 7)] = f2bf(p);
            }
            int prow = w * 32 + l31;
            bf16x8 pa0 = *(const bf16x8*)(p_lds + prow * 32 + ((hi ^ (l31 & 3)) * 8));
            bf16x8 pa1 = *(const bf16x8*)(p_lds + prow * 32 + (((2 + hi) ^ (l31 & 3)) * 8));

            // O += P V^T
            __builtin_amdgcn_s_setprio(1);
            #pragma unroll
            for (int cb = 0; cb < 8; cb++) {
                int c = cb * 32 + l31;
                int vb0 = c * 64 + jh * 32 + hi * 8;
                int xv = (c & 7) * 8;
                bf16x8 v0 = *(const bf16x8*)(vl + ((vb0 + 0) ^ xv));
                MFMA32(O[cb], pa0, v0);
                bf16x8 v1 = *(const bf16x8*)(vl + ((vb0 + 16) ^ xv));
                MFMA32(O[cb], pa1, v1);
            }
            __builtin_amdgcn_s_setprio(0);
        }

        // stage next tile now (loads + writes in one tight window; minimal liveness)
        if (it + 1 < niter) stage_tile(d ^ 1, jbase + (it + 1) * 64);
    }

    // epilogue: reduce l over the 32 col-lanes (rows live per (e,hi))
    #pragma unroll
    for (int e = 0; e < 16; e++) {
        float rs = l_r[e];
        rs += __shfl_xor(rs, 1, 64);
        rs += __shfl_xor(rs, 2, 64);
        rs += __shfl_xor(rs, 4, 64);
        rs += __shfl_xor(rs, 8, 64);
        rs += __shfl_xor(rs, 16, 64);
        l_r[e] = rs;
    }

    size_t obase = (size_t)(seg * BB + b) * NN + i0;
    #pragma unroll
    for (int e = 0; e < 16; e++) {
        int row = w * 32 + (e & 3) + 8 * (e >> 2) + 4 * hi;
        float* orow = O_part + (obase + row) * CC + l31;
        #pragma unroll
        for (int cb = 0; cb < 8; cb++) orow[cb * 32] = O[cb][e];
        if (l31 == 0) l_part[obase + row] = l_r[e];
    }
}

// ---------------- merge partial segments -> out_t bf16 ----------------
__global__ __launch_bounds__(256) void merge_kernel(
    const float* __restrict__ O_part, const float* __restrict__ l_part,
    ushort* __restrict__ out_t, int S)
{
    int b = blockIdx.y;
    int t = threadIdx.x;
    int i = blockIdx.x * 64 + (t >> 2);
    int c0 = (t & 3) * 64;

    float lsum = 0.f;
    for (int s = 0; s < S; s++)
        lsum += l_part[(size_t)(s * BB + b) * NN + i];
    float inv = 1.0f / fmaxf(lsum, 1e-20f);

    #pragma unroll 4
    for (int k = 0; k < 16; k++) {
        f32x4 acc = {0.f, 0.f, 0.f, 0.f};
        for (int s = 0; s < S; s++) {
            const float* op = O_part + ((size_t)(s * BB + b) * NN + i) * CC + c0 + k * 4;
            f32x4 v = *(const f32x4*)op;
            acc.x += v.x; acc.y += v.y; acc.z += v.z; acc.w += v.w;
        }
        ushort4 o;
        o.x = f2bf(acc.x * inv);
        o.y = f2bf(acc.y * inv);
        o.z = f2bf(acc.z * inv);
        o.w = f2bf(acc.w * inv);
        *(ushort4*)(out_t + (size_t)(b * NN + i) * CC + c0 + k * 4) = o;
    }
}

// ---------------- proj GEMM + bias + residual ----------------
__global__ __launch_bounds__(256) void proj_kernel(
    const ushort* __restrict__ out_t, const float* __restrict__ proj_w,
    const float* __restrict__ proj_b, const float* __restrict__ x,
    float* __restrict__ out)
{
    int b = blockIdx.z;
    int d0 = blockIdx.x * 64;
    int i0 = blockIdx.y * 256;
    int t = threadIdx.x, w = t >> 6, l = t & 63, l15 = l & 15, g = l >> 4;
    __shared__ ushort a_lds[64 * 256];

    #pragma unroll
    for (int it = 0; it < 8; it++) {
        int cid = it * 256 + t;
        int dd = cid >> 5, cc = cid & 31;
        const float* ap = proj_w + (d0 + dd) * CC + cc * 8;
        f32x4 u0 = *(const f32x4*)ap;
        f32x4 u1 = *(const f32x4*)(ap + 4);
        bf16x8 a;
        a[0] = (short)f2bf(u0.x); a[1] = (short)f2bf(u0.y);
        a[2] = (short)f2bf(u0.z); a[3] = (short)f2bf(u0.w);
        a[4] = (short)f2bf(u1.x); a[5] = (short)f2bf(u1.y);
        a[6] = (short)f2bf(u1.z); a[7] = (short)f2bf(u1.w);
        *(bf16x8*)(a_lds + dd * 256 + (cc ^ (dd & 7)) * 8) = a;
    }
    __syncthreads();

    f32x4 acc[16];
    #pragma unroll
    for (int it = 0; it < 16; it++) { f32x4 z = {0.f, 0.f, 0.f, 0.f}; acc[it] = z; }
    int dl = w * 16 + l15;
    #pragma unroll
    for (int kk = 0; kk < 8; kk++) {
        int cc = kk * 4 + g;
        bf16x8 af = *(const bf16x8*)(a_lds + dl * 256 + (cc ^ (dl & 7)) * 8);
        #pragma unroll
        for (int it = 0; it < 16; it++) {
            bf16x8 bfr = *(const bf16x8*)(out_t + (size_t)(b * NN + i0 + it * 16 + l15) * CC + kk * 32 + g * 8);
            MFMA16(acc[it], af, bfr);
        }
    }
    int dbase = d0 + w * 16 + g * 4;
    f32x4 pb = *(const f32x4*)(proj_b + dbase);
    #pragma unroll
    for (int it = 0; it < 16; it++) {
        int i = i0 + it * 16 + l15;
        #pragma unroll
        for (int e = 0; e < 4; e++) {
            int off = (b * CC + dbase + e) * NN + i;
            out[off] = acc[it][e] + pb[e] + x[off];
        }
    }
}

extern "C" void kernel_launch(void* const* d_in, const int* in_sizes, int n_in,
                              void* d_out, int out_size, void* d_ws, size_t ws_size,
                              hipStream_t stream) {
    const float* x      = (const float*)d_in[0];
    const float* gamma  = (const float*)d_in[1];
    const float* beta   = (const float*)d_in[2];
    const float* qkv_w  = (const float*)d_in[3];
    const float* qkv_b  = (const float*)d_in[4];
    const float* proj_w = (const float*)d_in[5];
    const float* proj_b = (const float*)d_in[6];
    float* out = (float*)d_out;

    char* ws = (char*)d_ws;
    float* part   = (float*)ws;
    float* stats  = (float*)(ws + 2048);
    ushort* xn_t  = (ushort*)(ws + 4096);
    ushort* q_t   = (ushort*)(ws + 4096 + 1ull * 8388608);
    ushort* k_t   = (ushort*)(ws + 4096 + 2ull * 8388608);
    ushort* v_g   = (ushort*)(ws + 4096 + 3ull * 8388608);
    ushort* out_t = xn_t;

    size_t mlbase = 4096 + 4ull * 8388608;            // l_part (<=1MB slot)
    float* l_part = (float*)(ws + mlbase);
    size_t obase  = mlbase + 1048576;
    float* O_part = (float*)(ws + obase);             // S * 16 MB

    int S = 1;
    if (ws_size >= obase + 4ull * 16777216) S = 4;
    else if (ws_size >= obase + 2ull * 16777216) S = 2;

    stats_part<<<dim3(64, 4), 256, 0, stream>>>(x, part);
    stats_final<<<1, 256, 0, stream>>>(part, stats);
    norm_t_kernel<<<dim3(128, 8, 4), 256, 0, stream>>>(x, gamma, beta, stats, xn_t);
    qkv_kernel<<<dim3(12, 64, 4), 256, 0, stream>>>(xn_t, qkv_w, qkv_b, q_t, k_t, v_g);
    flash_kernel<<<dim3(16, S, 4), 512, 0, stream>>>(q_t, k_t, v_g, O_part, l_part, NN / S);
    merge_kernel<<<dim3(64, 4), 256, 0, stream>>>(O_part, l_part, out_t, S);
    proj_kernel<<<dim3(4, 16, 4), 256, 0, stream>>>(out_t, proj_w, proj_b, x, out);
}

// Round 9
// 290.413 us; speedup vs baseline: 2.2634x; 2.2634x over previous
//
#include <hip/hip_runtime.h>

#define BB 4
#define CC 256
#define NN 4096
#define CNT (CC*NN)

typedef float f32x4 __attribute__((ext_vector_type(4)));
typedef short bf16x8 __attribute__((ext_vector_type(8)));

__device__ inline ushort f2bf(float f) {
    union { float f; uint u; } v; v.f = f;
    uint r = v.u + 0x7fff + ((v.u >> 16) & 1);
    return (ushort)(r >> 16);
}

#define MFMA16(d, a, b) d = __builtin_amdgcn_mfma_f32_16x16x32_bf16(a, b, d, 0, 0, 0)

// ---------------- stats: deterministic two-stage sum/sumsq per batch ----------------
__global__ __launch_bounds__(256) void stats_part(const float* __restrict__ x,
                                                  float* __restrict__ part) {
    int b = blockIdx.y;
    const float* xb = x + b * CNT;
    float s = 0.f, q = 0.f;
    int base = (blockIdx.x * 256 + threadIdx.x) * 4;
    for (int i = base; i < CNT; i += 64 * 256 * 4) {
        f32x4 v = *(const f32x4*)(xb + i);
        s += (v.x + v.y) + (v.z + v.w);
        q += (v.x * v.x + v.y * v.y) + (v.z * v.z + v.w * v.w);
    }
    for (int off = 32; off; off >>= 1) {
        s += __shfl_down(s, off, 64);
        q += __shfl_down(q, off, 64);
    }
    __shared__ float red[8];
    int lane = threadIdx.x & 63, wv = threadIdx.x >> 6;
    if (!lane) { red[wv * 2] = s; red[wv * 2 + 1] = q; }
    __syncthreads();
    if (threadIdx.x == 0) {
        part[(b * 64 + blockIdx.x) * 2 + 0] = red[0] + red[2] + red[4] + red[6];
        part[(b * 64 + blockIdx.x) * 2 + 1] = red[1] + red[3] + red[5] + red[7];
    }
}

__global__ __launch_bounds__(256) void stats_final(const float* __restrict__ part,
                                                   float* __restrict__ stats) {
    int t = threadIdx.x;
    int b = t >> 6, lane = t & 63;
    float s = part[(b * 64 + lane) * 2 + 0];
    float q = part[(b * 64 + lane) * 2 + 1];
    for (int off = 32; off; off >>= 1) {
        s += __shfl_down(s, off, 64);
        q += __shfl_down(q, off, 64);
    }
    if (lane == 0) { stats[b * 2] = s; stats[b * 2 + 1] = q; }
}

// ---------------- norm + transpose: x[b][c][n] fp32 -> xn_t[b][n][c] bf16 ----------------
__global__ __launch_bounds__(256) void norm_t_kernel(
    const float* __restrict__ x, const float* __restrict__ gamma,
    const float* __restrict__ beta, const float* __restrict__ stats,
    ushort* __restrict__ xn_t)
{
    int b = blockIdx.z;
    float mean = stats[b * 2] * (1.0f / (float)CNT);
    float var = stats[b * 2 + 1] * (1.0f / (float)CNT) - mean * mean;
    float rinv = rsqrtf(var + 1e-5f);
    int n0 = blockIdx.x * 32, c0 = blockIdx.y * 32;
    __shared__ float tl[32][33];
    int tr = threadIdx.x >> 3;
    int tc4 = (threadIdx.x & 7) * 4;
    int c = c0 + tr;
    float gsc = gamma[c] * rinv;
    float bsc = beta[c] - mean * gsc;
    f32x4 v = *(const f32x4*)(x + ((b * CC + c) * NN + n0 + tc4));
    tl[tr][tc4 + 0] = v.x * gsc + bsc;
    tl[tr][tc4 + 1] = v.y * gsc + bsc;
    tl[tr][tc4 + 2] = v.z * gsc + bsc;
    tl[tr][tc4 + 3] = v.w * gsc + bsc;
    __syncthreads();
    int nr = threadIdx.x >> 3;
    int cg4 = (threadIdx.x & 7) * 4;
    ushort4 o;
    o.x = f2bf(tl[cg4 + 0][nr]);
    o.y = f2bf(tl[cg4 + 1][nr]);
    o.z = f2bf(tl[cg4 + 2][nr]);
    o.w = f2bf(tl[cg4 + 3][nr]);
    *(ushort4*)(xn_t + ((size_t)(b * NN + n0 + nr) * CC + c0 + cg4)) = o;
}

// ---------------- QKV GEMM: [768,256]x[256,4096] per batch, bf16 MFMA ----------------
// Q rows are PRE-SCALED by 2^-4 (= C^-0.5) so flash needs no scale.
__global__ __launch_bounds__(256) void qkv_kernel(
    const ushort* __restrict__ xn_t, const float* __restrict__ qkv_w,
    const float* __restrict__ qkv_b, ushort* __restrict__ q_t,
    ushort* __restrict__ k_t, ushort* __restrict__ v_g)
{
    int b = blockIdx.z;
    int d0 = blockIdx.x * 64;
    int i0 = blockIdx.y * 64;
    int t = threadIdx.x, w = t >> 6, l = t & 63, l15 = l & 15, g = l >> 4;
    __shared__ ushort b_lds[64 * 256];

    #pragma unroll
    for (int it = 0; it < 8; it++) {
        int cid = it * 256 + t;
        int rr = cid >> 5, cc = cid & 31;
        bf16x8 vv = *(const bf16x8*)(xn_t + ((size_t)(b * NN + i0 + rr) * CC + cc * 8));
        *(bf16x8*)(b_lds + rr * 256 + (cc ^ (rr & 7)) * 8) = vv;
    }
    bf16x8 af[8];
    int drow = d0 + w * 16 + l15;
    #pragma unroll
    for (int kk = 0; kk < 8; kk++) {
        const float* ap = qkv_w + drow * CC + kk * 32 + g * 8;
        f32x4 u0 = *(const f32x4*)ap;
        f32x4 u1 = *(const f32x4*)(ap + 4);
        bf16x8 a;
        a[0] = (short)f2bf(u0.x); a[1] = (short)f2bf(u0.y);
        a[2] = (short)f2bf(u0.z); a[3] = (short)f2bf(u0.w);
        a[4] = (short)f2bf(u1.x); a[5] = (short)f2bf(u1.y);
        a[6] = (short)f2bf(u1.z); a[7] = (short)f2bf(u1.w);
        af[kk] = a;
    }
    __syncthreads();

    f32x4 acc[4];
    #pragma unroll
    for (int it = 0; it < 4; it++) { f32x4 z = {0.f, 0.f, 0.f, 0.f}; acc[it] = z; }
    #pragma unroll
    for (int kk = 0; kk < 8; kk++) {
        int cc = kk * 4 + g;
        #pragma unroll
        for (int it = 0; it < 4; it++) {
            int il = it * 16 + l15;
            bf16x8 bf = *(const bf16x8*)(b_lds + il * 256 + (cc ^ (il & 7)) * 8);
            MFMA16(acc[it], af[kk], bf);
        }
    }
    int dbase = d0 + w * 16 + g * 4;
    f32x4 bias = *(const f32x4*)(qkv_b + dbase);
    float qs = (d0 < 256) ? 0.0625f : 1.0f;
    #pragma unroll
    for (int it = 0; it < 4; it++) {
        int i = i0 + it * 16 + l15;
        if (d0 < 512) {
            ushort4 o;
            o.x = f2bf((acc[it][0] + bias[0]) * qs);
            o.y = f2bf((acc[it][1] + bias[1]) * qs);
            o.z = f2bf((acc[it][2] + bias[2]) * qs);
            o.w = f2bf((acc[it][3] + bias[3]) * qs);
            ushort* dst = (d0 < 256) ? q_t : k_t;
            int dl = dbase - ((d0 < 256) ? 0 : 256);
            *(ushort4*)(dst + ((size_t)(b * NN + i) * CC + dl)) = o;
        } else {
            #pragma unroll
            for (int e = 0; e < 4; e++)
                v_g[(size_t)(b * CC + (dbase - 512 + e)) * NN + i] = f2bf(acc[it][e] + bias[e]);
        }
    }
}

// ---------------- flash attention: 16x16 MFMA, TWO 16-row blocks per wave ----------------
// 32 rows/wave, 8 waves = 256 rows/block. K/V fragments read once, used by both
// row-blocks (halves LDS reads/row vs R5). No-max softmax. KVBLK=32 double-buffered,
// one barrier/iter. Regs ~248 <= 256 (2 waves/SIMD).
__global__ __launch_bounds__(512, 2) void flash_kernel(
    const ushort* __restrict__ q_t, const ushort* __restrict__ k_t,
    const ushort* __restrict__ v_g, float* __restrict__ O_part,
    float* __restrict__ l_part, int segn)
{
    int b = blockIdx.z, seg = blockIdx.y;
    int i0 = blockIdx.x * 256;
    int jbase = seg * segn;
    int t = threadIdx.x, w = t >> 6, l = t & 63, l15 = l & 15, g = l >> 4;

    __shared__ ushort k_lds[2][32 * 256];  // [j][16B chunk ^ (j&7)]        16 KB x2
    __shared__ ushort v_lds[2][256 * 32];  // [c][16B chunk ^ s4(c)]        16 KB x2
    __shared__ ushort p_lds[256 * 32];     // [row][16B chunk ^ s4(row)]    16 KB

    // Q A-fragments for both row-blocks: row = i0 + w*32 + rb*16 + l15
    bf16x8 qf0[8], qf1[8];
    const ushort* qr0 = q_t + (size_t)(b * NN + i0 + w * 32 + l15) * CC + g * 8;
    #pragma unroll
    for (int kk = 0; kk < 8; kk++) qf0[kk] = *(const bf16x8*)(qr0 + kk * 32);
    const ushort* qr1 = qr0 + (size_t)16 * CC;
    #pragma unroll
    for (int kk = 0; kk < 8; kk++) qf1[kk] = *(const bf16x8*)(qr1 + kk * 32);

    f32x4 O0[16], O1[16];
    #pragma unroll
    for (int tc = 0; tc < 16; tc++) {
        f32x4 z = {0.f, 0.f, 0.f, 0.f};
        O0[tc] = z; O1[tc] = z;
    }
    float l0[4], l1[4];
    #pragma unroll
    for (int e = 0; e < 4; e++) { l0[e] = 0.f; l1[e] = 0.f; }

    const ushort* kb = k_t + (size_t)b * NN * CC;
    const ushort* vb = v_g + (size_t)b * CC * NN;

    // stage 32-j tile at absolute j = jt into buffer d (regs live only here)
    auto stage_tile = [&](int d, int jt) {
        bf16x8 kr[2], vr[2];
        #pragma unroll
        for (int is = 0; is < 2; is++) {
            int s = is * 512 + t;
            kr[is] = *(const bf16x8*)(kb + (size_t)(jt + (s >> 5)) * CC + (s & 31) * 8);
            vr[is] = *(const bf16x8*)(vb + (size_t)(s >> 2) * NN + jt + (s & 3) * 8);
        }
        #pragma unroll
        for (int is = 0; is < 2; is++) {
            int s = is * 512 + t;
            int jr = s >> 5, cc = s & 31;
            *(bf16x8*)((ushort*)k_lds[d] + jr * 256 + ((cc ^ (jr & 7)) * 8)) = kr[is];
            int cr = s >> 2, cv = s & 3;
            *(bf16x8*)((ushort*)v_lds[d] + cr * 32 + ((cv ^ ((cr ^ (cr >> 2)) & 3)) * 8)) = vr[is];
        }
    };

    stage_tile(0, jbase);
    int niter = segn >> 5;

    for (int it = 0; it < niter; it++) {
        int d = it & 1;
        __syncthreads();                 // buf d ready; prev readers done
        const ushort* kl = k_lds[d];
        const ushort* vl = v_lds[d];

        // S = Q K^T, per 16-col group; softmax immediately (sj liveness = 8 regs)
        #pragma unroll
        for (int jg = 0; jg < 2; jg++) {
            f32x4 s0 = {0.f, 0.f, 0.f, 0.f}, s1 = {0.f, 0.f, 0.f, 0.f};
            int j = jg * 16 + l15;
            const ushort* krow = kl + j * 256;
            int xj = j & 7;
            __builtin_amdgcn_s_setprio(1);
            #pragma unroll
            for (int kk = 0; kk < 8; kk++) {
                bf16x8 bk = *(const bf16x8*)(krow + (((kk * 4 + g) ^ xj) * 8));
                MFMA16(s0, qf0[kk], bk);      // B fragment shared by both row-blocks
                MFMA16(s1, qf1[kk], bk);
            }
            __builtin_amdgcn_s_setprio(0);
            int ch = jg * 2 + (l15 >> 3);     // original 8-j chunk of column j
            int j7 = l15 & 7;
            #pragma unroll
            for (int e = 0; e < 4; e++) {
                float p0 = __expf(s0[e]);
                float p1 = __expf(s1[e]);
                l0[e] += p0; l1[e] += p1;
                int r0 = w * 32 + g * 4 + e;
                int r1 = r0 + 16;
                p_lds[r0 * 32 + ((ch ^ ((r0 ^ (r0 >> 2)) & 3)) * 8) + j7] = f2bf(p0);
                p_lds[r1 * 32 + ((ch ^ ((r1 ^ (r1 >> 2)) & 3)) * 8) + j7] = f2bf(p1);
            }
        }

        // read P A-fragments (wave-private rows; lgkmcnt orders write->read)
        int pr0 = w * 32 + l15, pr1 = pr0 + 16;
        bf16x8 pa0 = *(const bf16x8*)(p_lds + pr0 * 32 + ((g ^ ((pr0 ^ (pr0 >> 2)) & 3)) * 8));
        bf16x8 pa1 = *(const bf16x8*)(p_lds + pr1 * 32 + ((g ^ ((pr1 ^ (pr1 >> 2)) & 3)) * 8));

        // O += P V^T (V fragment shared by both row-blocks)
        __builtin_amdgcn_s_setprio(1);
        #pragma unroll
        for (int tc = 0; tc < 16; tc++) {
            int c = tc * 16 + l15;
            bf16x8 vf = *(const bf16x8*)(vl + c * 32 + ((g ^ ((c ^ (c >> 2)) & 3)) * 8));
            MFMA16(O0[tc], pa0, vf);
            MFMA16(O1[tc], pa1, vf);
        }
        __builtin_amdgcn_s_setprio(0);

        if (it + 1 < niter) stage_tile(d ^ 1, jbase + (it + 1) * 32);
    }

    // epilogue: reduce lane-local l across the 16-lane group
    #pragma unroll
    for (int e = 0; e < 4; e++) {
        float r0 = l0[e], r1 = l1[e];
        r0 += __shfl_xor(r0, 1, 64); r1 += __shfl_xor(r1, 1, 64);
        r0 += __shfl_xor(r0, 2, 64); r1 += __shfl_xor(r1, 2, 64);
        r0 += __shfl_xor(r0, 4, 64); r1 += __shfl_xor(r1, 4, 64);
        r0 += __shfl_xor(r0, 8, 64); r1 += __shfl_xor(r1, 8, 64);
        l0[e] = r0; l1[e] = r1;
    }

    size_t obase = (size_t)(seg * BB + b) * NN + i0;
    #pragma unroll
    for (int e = 0; e < 4; e++) {
        int r0 = w * 32 + g * 4 + e;
        float* orow0 = O_part + (obase + r0) * CC + l15;
        float* orow1 = O_part + (obase + r0 + 16) * CC + l15;
        #pragma unroll
        for (int tc = 0; tc < 16; tc++) {
            orow0[tc * 16] = O0[tc][e];
            orow1[tc * 16] = O1[tc][e];
        }
        if (l15 == 0) {
            l_part[obase + r0] = l0[e];
            l_part[obase + r0 + 16] = l1[e];
        }
    }
}

// ---------------- merge partial segments -> out_t bf16 ----------------
__global__ __launch_bounds__(256) void merge_kernel(
    const float* __restrict__ O_part, const float* __restrict__ l_part,
    ushort* __restrict__ out_t, int S)
{
    int b = blockIdx.y;
    int t = threadIdx.x;
    int i = blockIdx.x * 64 + (t >> 2);
    int c0 = (t & 3) * 64;

    float lsum = 0.f;
    for (int s = 0; s < S; s++)
        lsum += l_part[(size_t)(s * BB + b) * NN + i];
    float inv = 1.0f / fmaxf(lsum, 1e-20f);

    #pragma unroll 4
    for (int k = 0; k < 16; k++) {
        f32x4 acc = {0.f, 0.f, 0.f, 0.f};
        for (int s = 0; s < S; s++) {
            const float* op = O_part + ((size_t)(s * BB + b) * NN + i) * CC + c0 + k * 4;
            f32x4 v = *(const f32x4*)op;
            acc.x += v.x; acc.y += v.y; acc.z += v.z; acc.w += v.w;
        }
        ushort4 o;
        o.x = f2bf(acc.x * inv);
        o.y = f2bf(acc.y * inv);
        o.z = f2bf(acc.z * inv);
        o.w = f2bf(acc.w * inv);
        *(ushort4*)(out_t + (size_t)(b * NN + i) * CC + c0 + k * 4) = o;
    }
}

// ---------------- proj GEMM + bias + residual ----------------
__global__ __launch_bounds__(256) void proj_kernel(
    const ushort* __restrict__ out_t, const float* __restrict__ proj_w,
    const float* __restrict__ proj_b, const float* __restrict__ x,
    float* __restrict__ out)
{
    int b = blockIdx.z;
    int d0 = blockIdx.x * 64;
    int i0 = blockIdx.y * 256;
    int t = threadIdx.x, w = t >> 6, l = t & 63, l15 = l & 15, g = l >> 4;
    __shared__ ushort a_lds[64 * 256];

    #pragma unroll
    for (int it = 0; it < 8; it++) {
        int cid = it * 256 + t;
        int dd = cid >> 5, cc = cid & 31;
        const float* ap = proj_w + (d0 + dd) * CC + cc * 8;
        f32x4 u0 = *(const f32x4*)ap;
        f32x4 u1 = *(const f32x4*)(ap + 4);
        bf16x8 a;
        a[0] = (short)f2bf(u0.x); a[1] = (short)f2bf(u0.y);
        a[2] = (short)f2bf(u0.z); a[3] = (short)f2bf(u0.w);
        a[4] = (short)f2bf(u1.x); a[5] = (short)f2bf(u1.y);
        a[6] = (short)f2bf(u1.z); a[7] = (short)f2bf(u1.w);
        *(bf16x8*)(a_lds + dd * 256 + (cc ^ (dd & 7)) * 8) = a;
    }
    __syncthreads();

    f32x4 acc[16];
    #pragma unroll
    for (int it = 0; it < 16; it++) { f32x4 z = {0.f, 0.f, 0.f, 0.f}; acc[it] = z; }
    int dl = w * 16 + l15;
    #pragma unroll
    for (int kk = 0; kk < 8; kk++) {
        int cc = kk * 4 + g;
        bf16x8 af = *(const bf16x8*)(a_lds + dl * 256 + (cc ^ (dl & 7)) * 8);
        #pragma unroll
        for (int it = 0; it < 16; it++) {
            bf16x8 bfr = *(const bf16x8*)(out_t + (size_t)(b * NN + i0 + it * 16 + l15) * CC + kk * 32 + g * 8);
            MFMA16(acc[it], af, bfr);
        }
    }
    int dbase = d0 + w * 16 + g * 4;
    f32x4 pb = *(const f32x4*)(proj_b + dbase);
    #pragma unroll
    for (int it = 0; it < 16; it++) {
        int i = i0 + it * 16 + l15;
        #pragma unroll
        for (int e = 0; e < 4; e++) {
            int off = (b * CC + dbase + e) * NN + i;
            out[off] = acc[it][e] + pb[e] + x[off];
        }
    }
}

extern "C" void kernel_launch(void* const* d_in, const int* in_sizes, int n_in,
                              void* d_out, int out_size, void* d_ws, size_t ws_size,
                              hipStream_t stream) {
    const float* x      = (const float*)d_in[0];
    const float* gamma  = (const float*)d_in[1];
    const float* beta   = (const float*)d_in[2];
    const float* qkv_w  = (const float*)d_in[3];
    const float* qkv_b  = (const float*)d_in[4];
    const float* proj_w = (const float*)d_in[5];
    const float* proj_b = (const float*)d_in[6];
    float* out = (float*)d_out;

    char* ws = (char*)d_ws;
    float* part   = (float*)ws;
    float* stats  = (float*)(ws + 2048);
    ushort* xn_t  = (ushort*)(ws + 4096);
    ushort* q_t   = (ushort*)(ws + 4096 + 1ull * 8388608);
    ushort* k_t   = (ushort*)(ws + 4096 + 2ull * 8388608);
    ushort* v_g   = (ushort*)(ws + 4096 + 3ull * 8388608);
    ushort* out_t = xn_t;

    size_t mlbase = 4096 + 4ull * 8388608;            // l_part (<=1MB slot)
    float* l_part = (float*)(ws + mlbase);
    size_t obase  = mlbase + 1048576;
    float* O_part = (float*)(ws + obase);             // S * 16 MB

    int S = 1;
    if (ws_size >= obase + 4ull * 16777216) S = 4;
    else if (ws_size >= obase + 2ull * 16777216) S = 2;

    stats_part<<<dim3(64, 4), 256, 0, stream>>>(x, part);
    stats_final<<<1, 256, 0, stream>>>(part, stats);
    norm_t_kernel<<<dim3(128, 8, 4), 256, 0, stream>>>(x, gamma, beta, stats, xn_t);
    qkv_kernel<<<dim3(12, 64, 4), 256, 0, stream>>>(xn_t, qkv_w, qkv_b, q_t, k_t, v_g);
    flash_kernel<<<dim3(16, S, 4), 512, 0, stream>>>(q_t, k_t, v_g, O_part, l_part, NN / S);
    merge_kernel<<<dim3(64, 4), 256, 0, stream>>>(O_part, l_part, out_t, S);
    proj_kernel<<<dim3(4, 16, 4), 256, 0, stream>>>(out_t, proj_w, proj_b, x, out);
}

// Round 10
// 202.483 us; speedup vs baseline: 3.2463x; 1.4343x over previous
//
#include <hip/hip_runtime.h>

#define BB 4
#define CC 256
#define NN 4096
#define CNT (CC*NN)

typedef float f32x4 __attribute__((ext_vector_type(4)));
typedef short bf16x8 __attribute__((ext_vector_type(8)));

__device__ inline ushort f2bf(float f) {
    union { float f; uint u; } v; v.f = f;
    uint r = v.u + 0x7fff + ((v.u >> 16) & 1);
    return (ushort)(r >> 16);
}

__device__ inline uint cvt_pk_bf16(float a, float b) {
    uint r;
    asm("v_cvt_pk_bf16_f32 %0, %1, %2" : "=v"(r) : "v"(a), "v"(b));
    return r;
}

#define MFMA16(d, a, b) d = __builtin_amdgcn_mfma_f32_16x16x32_bf16(a, b, d, 0, 0, 0)

// ---------------- stats: deterministic two-stage sum/sumsq per batch ----------------
__global__ __launch_bounds__(256) void stats_part(const float* __restrict__ x,
                                                  float* __restrict__ part) {
    int b = blockIdx.y;
    const float* xb = x + b * CNT;
    float s = 0.f, q = 0.f;
    int base = (blockIdx.x * 256 + threadIdx.x) * 4;
    for (int i = base; i < CNT; i += 64 * 256 * 4) {
        f32x4 v = *(const f32x4*)(xb + i);
        s += (v.x + v.y) + (v.z + v.w);
        q += (v.x * v.x + v.y * v.y) + (v.z * v.z + v.w * v.w);
    }
    for (int off = 32; off; off >>= 1) {
        s += __shfl_down(s, off, 64);
        q += __shfl_down(q, off, 64);
    }
    __shared__ float red[8];
    int lane = threadIdx.x & 63, wv = threadIdx.x >> 6;
    if (!lane) { red[wv * 2] = s; red[wv * 2 + 1] = q; }
    __syncthreads();
    if (threadIdx.x == 0) {
        part[(b * 64 + blockIdx.x) * 2 + 0] = red[0] + red[2] + red[4] + red[6];
        part[(b * 64 + blockIdx.x) * 2 + 1] = red[1] + red[3] + red[5] + red[7];
    }
}

__global__ __launch_bounds__(256) void stats_final(const float* __restrict__ part,
                                                   float* __restrict__ stats) {
    int t = threadIdx.x;
    int b = t >> 6, lane = t & 63;
    float s = part[(b * 64 + lane) * 2 + 0];
    float q = part[(b * 64 + lane) * 2 + 1];
    for (int off = 32; off; off >>= 1) {
        s += __shfl_down(s, off, 64);
        q += __shfl_down(q, off, 64);
    }
    if (lane == 0) { stats[b * 2] = s; stats[b * 2 + 1] = q; }
}

// ---------------- norm + transpose: x[b][c][n] fp32 -> xn_t[b][n][c] bf16 ----------------
__global__ __launch_bounds__(256) void norm_t_kernel(
    const float* __restrict__ x, const float* __restrict__ gamma,
    const float* __restrict__ beta, const float* __restrict__ stats,
    ushort* __restrict__ xn_t)
{
    int b = blockIdx.z;
    float mean = stats[b * 2] * (1.0f / (float)CNT);
    float var = stats[b * 2 + 1] * (1.0f / (float)CNT) - mean * mean;
    float rinv = rsqrtf(var + 1e-5f);
    int n0 = blockIdx.x * 32, c0 = blockIdx.y * 32;
    __shared__ float tl[32][33];
    int tr = threadIdx.x >> 3;
    int tc4 = (threadIdx.x & 7) * 4;
    int c = c0 + tr;
    float gsc = gamma[c] * rinv;
    float bsc = beta[c] - mean * gsc;
    f32x4 v = *(const f32x4*)(x + ((b * CC + c) * NN + n0 + tc4));
    tl[tr][tc4 + 0] = v.x * gsc + bsc;
    tl[tr][tc4 + 1] = v.y * gsc + bsc;
    tl[tr][tc4 + 2] = v.z * gsc + bsc;
    tl[tr][tc4 + 3] = v.w * gsc + bsc;
    __syncthreads();
    int nr = threadIdx.x >> 3;
    int cg4 = (threadIdx.x & 7) * 4;
    ushort4 o;
    o.x = f2bf(tl[cg4 + 0][nr]);
    o.y = f2bf(tl[cg4 + 1][nr]);
    o.z = f2bf(tl[cg4 + 2][nr]);
    o.w = f2bf(tl[cg4 + 3][nr]);
    *(ushort4*)(xn_t + ((size_t)(b * NN + n0 + nr) * CC + c0 + cg4)) = o;
}

// ---------------- QKV GEMM: [768,256]x[256,4096] per batch, bf16 MFMA ----------------
// Q rows are PRE-SCALED by 2^-4 * log2(e) so flash uses exp2 directly.
__global__ __launch_bounds__(256) void qkv_kernel(
    const ushort* __restrict__ xn_t, const float* __restrict__ qkv_w,
    const float* __restrict__ qkv_b, ushort* __restrict__ q_t,
    ushort* __restrict__ k_t, ushort* __restrict__ v_g)
{
    int b = blockIdx.z;
    int d0 = blockIdx.x * 64;
    int i0 = blockIdx.y * 64;
    int t = threadIdx.x, w = t >> 6, l = t & 63, l15 = l & 15, g = l >> 4;
    __shared__ ushort b_lds[64 * 256];

    #pragma unroll
    for (int it = 0; it < 8; it++) {
        int cid = it * 256 + t;
        int rr = cid >> 5, cc = cid & 31;
        bf16x8 vv = *(const bf16x8*)(xn_t + ((size_t)(b * NN + i0 + rr) * CC + cc * 8));
        *(bf16x8*)(b_lds + rr * 256 + (cc ^ (rr & 7)) * 8) = vv;
    }
    bf16x8 af[8];
    int drow = d0 + w * 16 + l15;
    #pragma unroll
    for (int kk = 0; kk < 8; kk++) {
        const float* ap = qkv_w + drow * CC + kk * 32 + g * 8;
        f32x4 u0 = *(const f32x4*)ap;
        f32x4 u1 = *(const f32x4*)(ap + 4);
        bf16x8 a;
        a[0] = (short)f2bf(u0.x); a[1] = (short)f2bf(u0.y);
        a[2] = (short)f2bf(u0.z); a[3] = (short)f2bf(u0.w);
        a[4] = (short)f2bf(u1.x); a[5] = (short)f2bf(u1.y);
        a[6] = (short)f2bf(u1.z); a[7] = (short)f2bf(u1.w);
        af[kk] = a;
    }
    __syncthreads();

    f32x4 acc[4];
    #pragma unroll
    for (int it = 0; it < 4; it++) { f32x4 z = {0.f, 0.f, 0.f, 0.f}; acc[it] = z; }
    #pragma unroll
    for (int kk = 0; kk < 8; kk++) {
        int cc = kk * 4 + g;
        #pragma unroll
        for (int it = 0; it < 4; it++) {
            int il = it * 16 + l15;
            bf16x8 bf = *(const bf16x8*)(b_lds + il * 256 + (cc ^ (il & 7)) * 8);
            MFMA16(acc[it], af[kk], bf);
        }
    }
    int dbase = d0 + w * 16 + g * 4;
    f32x4 bias = *(const f32x4*)(qkv_b + dbase);
    float qs = (d0 < 256) ? 0.0625f * 1.4426950408889634f : 1.0f;  // fold log2(e)
    #pragma unroll
    for (int it = 0; it < 4; it++) {
        int i = i0 + it * 16 + l15;
        if (d0 < 512) {
            ushort4 o;
            o.x = f2bf((acc[it][0] + bias[0]) * qs);
            o.y = f2bf((acc[it][1] + bias[1]) * qs);
            o.z = f2bf((acc[it][2] + bias[2]) * qs);
            o.w = f2bf((acc[it][3] + bias[3]) * qs);
            ushort* dst = (d0 < 256) ? q_t : k_t;
            int dl = dbase - ((d0 < 256) ? 0 : 256);
            *(ushort4*)(dst + ((size_t)(b * NN + i) * CC + dl)) = o;
        } else {
            #pragma unroll
            for (int e = 0; e < 4; e++)
                v_g[(size_t)(b * CC + (dbase - 512 + e)) * NN + i] = f2bf(acc[it][e] + bias[e]);
        }
    }
}

// ---------------- flash attention: swapped QK^T (P row lane-local) ----------------
// 16x16 MFMA, two 16-row blocks/wave, 8 waves = 256 rows/block. MFMA(K,Q) puts
// P[i=l15][j..] per lane -> P staged via 2 cvt_pk + ONE b64 write per jg per rb
// (no scalar scatter, minimal conflicts); l is one scalar per rb. exp2 (Q pre-scaled).
__global__ __launch_bounds__(512, 2) void flash_kernel(
    const ushort* __restrict__ q_t, const ushort* __restrict__ k_t,
    const ushort* __restrict__ v_g, float* __restrict__ O_part,
    float* __restrict__ l_part, int segn)
{
    int b = blockIdx.z, seg = blockIdx.y;
    int i0 = blockIdx.x * 256;
    int jbase = seg * segn;
    int t = threadIdx.x, w = t >> 6, l = t & 63, l15 = l & 15, g = l >> 4;

    __shared__ ushort k_lds[2][32 * 256];  // [j][16B chunk ^ (j&7)]
    __shared__ ushort v_lds[2][256 * 32];  // [c][16B chunk ^ s4(c)]
    __shared__ ushort p_lds[256 * 32];     // [r][16B chunk ^ (r&3)], halves by g&1

    bf16x8 qf0[8], qf1[8];
    const ushort* qr0 = q_t + (size_t)(b * NN + i0 + w * 32 + l15) * CC + g * 8;
    #pragma unroll
    for (int kk = 0; kk < 8; kk++) qf0[kk] = *(const bf16x8*)(qr0 + kk * 32);
    const ushort* qr1 = qr0 + (size_t)16 * CC;
    #pragma unroll
    for (int kk = 0; kk < 8; kk++) qf1[kk] = *(const bf16x8*)(qr1 + kk * 32);

    f32x4 O0[16], O1[16];
    #pragma unroll
    for (int tc = 0; tc < 16; tc++) {
        f32x4 z = {0.f, 0.f, 0.f, 0.f};
        O0[tc] = z; O1[tc] = z;
    }
    float l0 = 0.f, l1 = 0.f;   // partial denom for row i = w*32 + (0|16) + l15

    const ushort* kb = k_t + (size_t)b * NN * CC;
    const ushort* vb = v_g + (size_t)b * CC * NN;

    auto stage_tile = [&](int d, int jt) {
        bf16x8 kr[2], vr[2];
        #pragma unroll
        for (int is = 0; is < 2; is++) {
            int s = is * 512 + t;
            kr[is] = *(const bf16x8*)(kb + (size_t)(jt + (s >> 5)) * CC + (s & 31) * 8);
            vr[is] = *(const bf16x8*)(vb + (size_t)(s >> 2) * NN + jt + (s & 3) * 8);
        }
        #pragma unroll
        for (int is = 0; is < 2; is++) {
            int s = is * 512 + t;
            int jr = s >> 5, cc = s & 31;
            *(bf16x8*)((ushort*)k_lds[d] + jr * 256 + ((cc ^ (jr & 7)) * 8)) = kr[is];
            int cr = s >> 2, cv = s & 3;
            *(bf16x8*)((ushort*)v_lds[d] + cr * 32 + ((cv ^ ((cr ^ (cr >> 2)) & 3)) * 8)) = vr[is];
        }
    };

    stage_tile(0, jbase);
    int niter = segn >> 5;

    int r0 = w * 32 + l15;           // p_lds row for rb0 (rb1: +16)
    int half = (g & 1) * 4;          // ushort offset within 16B chunk

    for (int it = 0; it < niter; it++) {
        int d = it & 1;
        __syncthreads();
        const ushort* kl = k_lds[d];
        const ushort* vl = v_lds[d];

        // S^T = K Q^T per 16-j group: lane holds S[j=jg*16+g*4+e][i=l15]
        #pragma unroll
        for (int jg = 0; jg < 2; jg++) {
            f32x4 s0 = {0.f, 0.f, 0.f, 0.f}, s1 = {0.f, 0.f, 0.f, 0.f};
            int j = jg * 16 + l15;
            const ushort* krow = kl + j * 256;
            int xj = j & 7;
            __builtin_amdgcn_s_setprio(1);
            #pragma unroll
            for (int kk = 0; kk < 8; kk++) {
                bf16x8 bk = *(const bf16x8*)(krow + (((kk * 4 + g) ^ xj) * 8));
                MFMA16(s0, bk, qf0[kk]);      // swapped: A=K, B=Q
                MFMA16(s1, bk, qf1[kk]);
            }
            __builtin_amdgcn_s_setprio(0);

            // p = exp2(S) (log2e folded into Q); pack 4 consecutive j as 2x u32
            float p00 = exp2f(s0[0]), p01 = exp2f(s0[1]);
            float p02 = exp2f(s0[2]), p03 = exp2f(s0[3]);
            float p10 = exp2f(s1[0]), p11 = exp2f(s1[1]);
            float p12 = exp2f(s1[2]), p13 = exp2f(s1[3]);
            l0 += (p00 + p01) + (p02 + p03);
            l1 += (p10 + p11) + (p12 + p13);
            uint lo0 = cvt_pk_bf16(p00, p01), hi0 = cvt_pk_bf16(p02, p03);
            uint lo1 = cvt_pk_bf16(p10, p11), hi1 = cvt_pk_bf16(p12, p13);
            int c16 = jg * 2 + (g >> 1);      // 16B chunk = j/8
            uint2 u0; u0.x = lo0; u0.y = hi0;
            uint2 u1; u1.x = lo1; u1.y = hi1;
            *(uint2*)(p_lds + r0 * 32 + ((c16 ^ (r0 & 3)) * 8) + half) = u0;
            int r1 = r0 + 16;
            *(uint2*)(p_lds + r1 * 32 + ((c16 ^ (r1 & 3)) * 8) + half) = u1;
        }

        // P A-fragments: row i=l15(+16), j = g*8..g*8+7 -> chunk16 index g
        bf16x8 pa0 = *(const bf16x8*)(p_lds + r0 * 32 + ((g ^ (r0 & 3)) * 8));
        int r1 = r0 + 16;
        bf16x8 pa1 = *(const bf16x8*)(p_lds + r1 * 32 + ((g ^ (r1 & 3)) * 8));

        // O += P V^T (V fragment shared by both row-blocks)
        __builtin_amdgcn_s_setprio(1);
        #pragma unroll
        for (int tc = 0; tc < 16; tc++) {
            int c = tc * 16 + l15;
            bf16x8 vf = *(const bf16x8*)(vl + c * 32 + ((g ^ ((c ^ (c >> 2)) & 3)) * 8));
            MFMA16(O0[tc], pa0, vf);
            MFMA16(O1[tc], pa1, vf);
        }
        __builtin_amdgcn_s_setprio(0);

        if (it + 1 < niter) stage_tile(d ^ 1, jbase + (it + 1) * 32);
    }

    // l lives per (l15, g): reduce across the 4 g-groups
    l0 += __shfl_xor(l0, 16, 64); l1 += __shfl_xor(l1, 16, 64);
    l0 += __shfl_xor(l0, 32, 64); l1 += __shfl_xor(l1, 32, 64);

    size_t obase = (size_t)(seg * BB + b) * NN + i0;
    if (g == 0) {
        l_part[obase + w * 32 + l15] = l0;
        l_part[obase + w * 32 + 16 + l15] = l1;
    }
    #pragma unroll
    for (int e = 0; e < 4; e++) {
        int ro = w * 32 + g * 4 + e;
        float* orow0 = O_part + (obase + ro) * CC + l15;
        float* orow1 = O_part + (obase + ro + 16) * CC + l15;
        #pragma unroll
        for (int tc = 0; tc < 16; tc++) {
            orow0[tc * 16] = O0[tc][e];
            orow1[tc * 16] = O1[tc][e];
        }
    }
}

// ---------------- merge partial segments -> out_t bf16 (fully coalesced) ----------------
__global__ __launch_bounds__(256) void merge_kernel(
    const float* __restrict__ O_part, const float* __restrict__ l_part,
    ushort* __restrict__ out_t, int S)
{
    int idx = blockIdx.x * 256 + threadIdx.x;   // f32x4 index over [BB*NN*CC/4]
    int row = idx >> 6;                          // b*NN + i
    float lsum = 0.f;
    for (int s = 0; s < S; s++) lsum += l_part[(size_t)s * BB * NN + row];
    float inv = 1.0f / fmaxf(lsum, 1e-20f);

    f32x4 acc = {0.f, 0.f, 0.f, 0.f};
    for (int s = 0; s < S; s++) {
        f32x4 v = *(const f32x4*)(O_part + ((size_t)s * BB * NN * CC) + (size_t)idx * 4);
        acc.x += v.x; acc.y += v.y; acc.z += v.z; acc.w += v.w;
    }
    ushort4 o;
    o.x = f2bf(acc.x * inv);
    o.y = f2bf(acc.y * inv);
    o.z = f2bf(acc.z * inv);
    o.w = f2bf(acc.w * inv);
    *(ushort4*)(out_t + (size_t)idx * 4) = o;
}

// ---------------- proj GEMM + bias + residual ----------------
__global__ __launch_bounds__(256) void proj_kernel(
    const ushort* __restrict__ out_t, const float* __restrict__ proj_w,
    const float* __restrict__ proj_b, const float* __restrict__ x,
    float* __restrict__ out)
{
    int b = blockIdx.z;
    int d0 = blockIdx.x * 64;
    int i0 = blockIdx.y * 256;
    int t = threadIdx.x, w = t >> 6, l = t & 63, l15 = l & 15, g = l >> 4;
    __shared__ ushort a_lds[64 * 256];

    #pragma unroll
    for (int it = 0; it < 8; it++) {
        int cid = it * 256 + t;
        int dd = cid >> 5, cc = cid & 31;
        const float* ap = proj_w + (d0 + dd) * CC + cc * 8;
        f32x4 u0 = *(const f32x4*)ap;
        f32x4 u1 = *(const f32x4*)(ap + 4);
        bf16x8 a;
        a[0] = (short)f2bf(u0.x); a[1] = (short)f2bf(u0.y);
        a[2] = (short)f2bf(u0.z); a[3] = (short)f2bf(u0.w);
        a[4] = (short)f2bf(u1.x); a[5] = (short)f2bf(u1.y);
        a[6] = (short)f2bf(u1.z); a[7] = (short)f2bf(u1.w);
        *(bf16x8*)(a_lds + dd * 256 + (cc ^ (dd & 7)) * 8) = a;
    }
    __syncthreads();

    f32x4 acc[16];
    #pragma unroll
    for (int it = 0; it < 16; it++) { f32x4 z = {0.f, 0.f, 0.f, 0.f}; acc[it] = z; }
    int dl = w * 16 + l15;
    #pragma unroll
    for (int kk = 0; kk < 8; kk++) {
        int cc = kk * 4 + g;
        bf16x8 af = *(const bf16x8*)(a_lds + dl * 256 + (cc ^ (dl & 7)) * 8);
        #pragma unroll
        for (int it = 0; it < 16; it++) {
            bf16x8 bfr = *(const bf16x8*)(out_t + (size_t)(b * NN + i0 + it * 16 + l15) * CC + kk * 32 + g * 8);
            MFMA16(acc[it], af, bfr);
        }
    }
    int dbase = d0 + w * 16 + g * 4;
    f32x4 pb = *(const f32x4*)(proj_b + dbase);
    #pragma unroll
    for (int it = 0; it < 16; it++) {
        int i = i0 + it * 16 + l15;
        #pragma unroll
        for (int e = 0; e < 4; e++) {
            int off = (b * CC + dbase + e) * NN + i;
            out[off] = acc[it][e] + pb[e] + x[off];
        }
    }
}

extern "C" void kernel_launch(void* const* d_in, const int* in_sizes, int n_in,
                              void* d_out, int out_size, void* d_ws, size_t ws_size,
                              hipStream_t stream) {
    const float* x      = (const float*)d_in[0];
    const float* gamma  = (const float*)d_in[1];
    const float* beta   = (const float*)d_in[2];
    const float* qkv_w  = (const float*)d_in[3];
    const float* qkv_b  = (const float*)d_in[4];
    const float* proj_w = (const float*)d_in[5];
    const float* proj_b = (const float*)d_in[6];
    float* out = (float*)d_out;

    char* ws = (char*)d_ws;
    float* part   = (float*)ws;
    float* stats  = (float*)(ws + 2048);
    ushort* xn_t  = (ushort*)(ws + 4096);
    ushort* q_t   = (ushort*)(ws + 4096 + 1ull * 8388608);
    ushort* k_t   = (ushort*)(ws + 4096 + 2ull * 8388608);
    ushort* v_g   = (ushort*)(ws + 4096 + 3ull * 8388608);
    ushort* out_t = xn_t;

    size_t mlbase = 4096 + 4ull * 8388608;
    float* l_part = (float*)(ws + mlbase);
    size_t obase  = mlbase + 1048576;
    float* O_part = (float*)(ws + obase);

    int S = 1;
    if (ws_size >= obase + 4ull * 16777216) S = 4;
    else if (ws_size >= obase + 2ull * 16777216) S = 2;

    stats_part<<<dim3(64, 4), 256, 0, stream>>>(x, part);
    stats_final<<<1, 256, 0, stream>>>(part, stats);
    norm_t_kernel<<<dim3(128, 8, 4), 256, 0, stream>>>(x, gamma, beta, stats, xn_t);
    qkv_kernel<<<dim3(12, 64, 4), 256, 0, stream>>>(xn_t, qkv_w, qkv_b, q_t, k_t, v_g);
    flash_kernel<<<dim3(16, S, 4), 512, 0, stream>>>(q_t, k_t, v_g, O_part, l_part, NN / S);
    merge_kernel<<<4096, 256, 0, stream>>>(O_part, l_part, out_t, S);
    proj_kernel<<<dim3(4, 16, 4), 256, 0, stream>>>(out_t, proj_w, proj_b, x, out);
}